// Round 2
// baseline (271.811 us; speedup 1.0000x reference)
//
#include <hip/hip_runtime.h>

#define CC 16
#define BB 16384
#define DD 256
#define BT 16
#define NT 512
#define SLAB ((size_t)BB * DD)   // floats per child slab

typedef float f32x4 __attribute__((ext_vector_type(4)));
typedef short bf16x8 __attribute__((ext_vector_type(8)));

__device__ __forceinline__ unsigned short f2bf(float f) {
    unsigned u = __builtin_bit_cast(unsigned, f);
    u += 0x7fffu + ((u >> 16) & 1u);
    return (unsigned short)(u >> 16);
}

__device__ __forceinline__ bf16x8 pack8(f32x4 a, f32x4 b) {
    bf16x8 v;
    v[0] = (short)f2bf(a[0]); v[1] = (short)f2bf(a[1]);
    v[2] = (short)f2bf(a[2]); v[3] = (short)f2bf(a[3]);
    v[4] = (short)f2bf(b[0]); v[5] = (short)f2bf(b[1]);
    v[6] = (short)f2bf(b[2]); v[7] = (short)f2bf(b[3]);
    return v;
}

__device__ __forceinline__ float sigm(float x) {
    return __builtin_amdgcn_rcpf(1.0f + __expf(-x));
}
__device__ __forceinline__ float tanhf_(float x) {
    return 2.0f * __builtin_amdgcn_rcpf(1.0f + __expf(-2.0f * x)) - 1.0f;
}

typedef __attribute__((address_space(3))) void lds_void;
typedef const __attribute__((address_space(1))) void gl_void;

__device__ __forceinline__ void stage16(const void* g, void* l) {
    __builtin_amdgcn_global_load_lds((gl_void*)g, (lds_void*)l, 16, 0, 0);
}

// Fused TreeLSTM node update, pipelined c-loop.
// Block: BT=16 batch rows x 256 cols, 8 waves (32 cols each), grid=1024.
// h staged f32 via global_load_lds (source-swizzled, LDS-linear); one raw
// s_barrier per child with counted vmcnt(8) so next-child staging loads
// stay in flight across the barrier; cm prefetched one child ahead.
__global__ __launch_bounds__(NT, 4) void treelstm(
    const float* __restrict__ cmem,   // [C][B][D] children_memory
    const float* __restrict__ chid,   // [C][B][D] children_hidden
    const float* __restrict__ Wf,     // [D][D]
    const float* __restrict__ bfv_g,  // [D]
    const float* __restrict__ Wiou,   // [3D][D]
    const float* __restrict__ biou,   // [3D]
    float* __restrict__ out)          // [2][B][D]
{
    __shared__ float hbuf[2][BT * DD];   // 2 x 16 KiB f32

    const int tid  = threadIdx.x;
    const int lane = tid & 63;
    const int wid  = tid >> 6;
    const int l15  = lane & 15;
    const int l4   = lane >> 4;    // 0..3
    const int b0   = blockIdx.x * BT;
    const int wc0  = wid * 32;     // this wave's 32 output columns

    // ---- Wf B-fragments in registers for the whole c-loop (2 n-frags x 8 k)
    bf16x8 wfr[2][8];
#pragma unroll
    for (int n = 0; n < 2; ++n) {
        const float* wrow = Wf + (size_t)(wc0 + n * 16 + l15) * DD + l4 * 8;
#pragma unroll
        for (int k = 0; k < 8; ++k) {
            f32x4 x0 = *(const f32x4*)(wrow + k * 32);
            f32x4 x1 = *(const f32x4*)(wrow + k * 32 + 4);
            wfr[n][k] = pack8(x0, x1);
        }
    }
    float bfr[2];
#pragma unroll
    for (int n = 0; n < 2; ++n) bfr[n] = bfv_g[wc0 + n * 16 + l15];

    // ---- staging: wave w stages rows {2w, 2w+1}; 64 lanes x 16B = one row.
    // LDS dest linear (base + lane*16); global source XOR-swizzled so the
    // ds_read side can use chunk ^= (row&7).
    const int r0 = wid * 2, r1 = r0 + 1;
    const char* g0 = (const char*)(chid + (size_t)(b0 + r0) * DD) + ((lane * 16) ^ ((r0 & 7) << 4));
    const char* g1 = (const char*)(chid + (size_t)(b0 + r1) * DD) + ((lane * 16) ^ ((r1 & 7) << 4));

    // cm loads in C-frag layout (rows l4*4+j, col wc0+n*16+l15)
    const float* cmp = cmem + (size_t)(b0 + l4 * 4) * DD + wc0 + l15;

    // ---- prologue: stage h(0), prefetch cm(0).  Order matters for vmcnt:
    // [stage x2, cm x8] outstanding at loop entry -> vmcnt(8) waits staging.
    stage16(g0, &hbuf[0][r0 * DD]);
    stage16(g1, &hbuf[0][r1 * DD]);
    g0 += SLAB * 4; g1 += SLAB * 4;

    float cmv[2][4];
#pragma unroll
    for (int n = 0; n < 2; ++n)
#pragma unroll
        for (int j = 0; j < 4; ++j)
            cmv[n][j] = cmp[j * DD + n * 16];
    const float* cmp_n = cmp + SLAB;

    float hs[8];
#pragma unroll
    for (int j = 0; j < 8; ++j) hs[j] = 0.0f;
    float nmv[2][4];
#pragma unroll
    for (int n = 0; n < 2; ++n)
#pragma unroll
        for (int j = 0; j < 4; ++j) nmv[n][j] = 0.0f;

    // A-frag LDS read addressing: row l15, global 16B-chunks {2*l4, 2*l4+1}
    // of each 8-chunk k-group, swizzle chunk ^= (row&7).
    const int rb = l15 * DD;
    const int c0 = (((2 * l4) ^ (l15 & 7)) << 2);
    const int c1 = (((2 * l4 + 1) ^ (l15 & 7)) << 2);

    for (int c = 0; c < CC; ++c) {
        // stage h(c) done (2 oldest retired); cm(c) may still fly (8 newest).
        asm volatile("s_waitcnt vmcnt(8)" ::: "memory");
        __builtin_amdgcn_s_barrier();

        // issue next child's staging into the other buffer — these 2 loads
        // stay in flight across the NEXT barrier (never drained mid-loop).
        if (c + 1 < CC) {
            stage16(g0, &hbuf[(c + 1) & 1][r0 * DD]);
            stage16(g1, &hbuf[(c + 1) & 1][r1 * DD]);
            g0 += SLAB * 4; g1 += SLAB * 4;
        }

        // forget-gate GEMM on h(c): read f32 from LDS, pack, MFMA
        f32x4 acc[2];
#pragma unroll
        for (int n = 0; n < 2; ++n)
            acc[n] = (f32x4){bfr[n], bfr[n], bfr[n], bfr[n]};

        const float* bc = &hbuf[c & 1][0];
#pragma unroll
        for (int kk = 0; kk < 8; ++kk) {
            f32x4 x0 = *(const f32x4*)(bc + rb + kk * 32 + c0);
            f32x4 x1 = *(const f32x4*)(bc + rb + kk * 32 + c1);
            if (kk == wid) {   // wave w owns k-chunk w: hidden_sum for free
#pragma unroll
                for (int j = 0; j < 4; ++j) { hs[j] += x0[j]; hs[4 + j] += x1[j]; }
            }
            bf16x8 a = pack8(x0, x1);
            acc[0] = __builtin_amdgcn_mfma_f32_16x16x32_bf16(a, wfr[0][kk], acc[0], 0, 0, 0);
            acc[1] = __builtin_amdgcn_mfma_f32_16x16x32_bf16(a, wfr[1][kk], acc[1], 0, 0, 0);
        }

        // node_memory += sigmoid(fg) * cm   (compiler emits counted vmcnt(2)
        // before first cmv use: stage h(c+1) stays outstanding)
#pragma unroll
        for (int n = 0; n < 2; ++n)
#pragma unroll
            for (int j = 0; j < 4; ++j)
                nmv[n][j] += sigm(acc[n][j]) * cmv[n][j];

        // prefetch cm(c+1) — a full iteration of latency to hide
        if (c + 1 < CC) {
#pragma unroll
            for (int n = 0; n < 2; ++n)
#pragma unroll
                for (int j = 0; j < 4; ++j)
                    cmv[n][j] = cmp_n[j * DD + n * 16];
            cmp_n += SLAB;
        }
    }

    // ---- epilogue: hidden_sum (f32) -> LDS buf0 at swizzled slots
    {
        float* hb = &hbuf[0][0];
        f32x4 lo, hi;
#pragma unroll
        for (int j = 0; j < 4; ++j) { lo[j] = hs[j]; hi[j] = hs[4 + j]; }
        *(f32x4*)(hb + rb + wid * 32 + c0) = lo;
        *(f32x4*)(hb + rb + wid * 32 + c1) = hi;
    }
    __syncthreads();

    // A-frags of hidden_sum, packed once, reused for all 3 iou chunks
    bf16x8 afr[8];
    {
        const float* hb = &hbuf[0][0];
#pragma unroll
        for (int kk = 0; kk < 8; ++kk) {
            f32x4 x0 = *(const f32x4*)(hb + rb + kk * 32 + c0);
            f32x4 x1 = *(const f32x4*)(hb + rb + kk * 32 + c1);
            afr[kk] = pack8(x0, x1);
        }
    }

    // iou GEMM: 3 gate chunks x 2 n-frags (Wiou frags loaded per (q,n))
    float gq[3][2][4];
#pragma unroll
    for (int q = 0; q < 3; ++q) {
#pragma unroll
        for (int n = 0; n < 2; ++n) {
            const float* wrow = Wiou + (size_t)(q * DD + wc0 + n * 16 + l15) * DD + l4 * 8;
            f32x4 acc = (f32x4){0.f, 0.f, 0.f, 0.f};
#pragma unroll
            for (int kk = 0; kk < 8; ++kk) {
                f32x4 x0 = *(const f32x4*)(wrow + kk * 32);
                f32x4 x1 = *(const f32x4*)(wrow + kk * 32 + 4);
                bf16x8 w = pack8(x0, x1);
                acc = __builtin_amdgcn_mfma_f32_16x16x32_bf16(afr[kk], w, acc, 0, 0, 0);
            }
            float bq = biou[q * DD + wc0 + n * 16 + l15];
#pragma unroll
            for (int j = 0; j < 4; ++j) gq[q][n][j] = acc[j] + bq;
        }
    }

    // ---- gates + stores
#pragma unroll
    for (int n = 0; n < 2; ++n)
#pragma unroll
        for (int j = 0; j < 4; ++j) {
            float ig = sigm(gq[0][n][j]);
            float og = sigm(gq[1][n][j]);
            float ug = tanhf_(gq[2][n][j]);
            float mm = nmv[n][j] + ig * ug;
            float hh = og * tanhf_(mm);
            int row = b0 + l4 * 4 + j;
            int col = wc0 + n * 16 + l15;
            out[(size_t)row * DD + col] = mm;
            out[(size_t)(BB * DD) + (size_t)row * DD + col] = hh;
        }
}

extern "C" void kernel_launch(void* const* d_in, const int* in_sizes, int n_in,
                              void* d_out, int out_size, void* d_ws, size_t ws_size,
                              hipStream_t stream) {
    const float* cmem = (const float*)d_in[0];  // children_memory [16][16384][256]
    const float* chid = (const float*)d_in[1];  // children_hidden [16][16384][256]
    const float* Wf   = (const float*)d_in[2];  // [256][256]
    const float* bf   = (const float*)d_in[3];  // [256]
    const float* Wiou = (const float*)d_in[4];  // [768][256]
    const float* biou = (const float*)d_in[5];  // [768]
    float* out = (float*)d_out;                 // [2][16384][256]

    treelstm<<<BB / BT, NT, 0, stream>>>(cmem, chid, Wf, bf, Wiou, biou, out);
}